// Round 11
// baseline (328.237 us; speedup 1.0000x reference)
//
#include <hip/hip_runtime.h>
#include <math.h>

typedef short bf16x8 __attribute__((ext_vector_type(8)));
typedef short short2v __attribute__((ext_vector_type(2)));
typedef short short4v __attribute__((ext_vector_type(4)));
typedef float f32x4 __attribute__((ext_vector_type(4)));

__device__ __forceinline__ float sspf(float x) {
    return __logf(1.0f + __expf(x)) - 0.6931471805599453f;
}
__device__ __forceinline__ short f2b(float f) {
    union { float f; unsigned u; } c; c.f = f;
    unsigned r = c.u + 0x7fff + ((c.u >> 16) & 1);
    return (short)(r >> 16);
}
__device__ __forceinline__ float b2f(short s) {
    union { unsigned u; float f; } c; c.u = ((unsigned)(unsigned short)s) << 16;
    return c.f;
}
__device__ __forceinline__ int rlanei(int v, int l) {
    return __builtin_amdgcn_readlane(v, l);
}
__device__ __forceinline__ float rlanef(float v, int l) {
    return __uint_as_float(__builtin_amdgcn_readlane(__float_as_uint(v), l));
}
__device__ __forceinline__ bf16x8 pack8(float4 a, float4 b) {
    bf16x8 o;
    o[0] = f2b(a.x); o[1] = f2b(a.y); o[2] = f2b(a.z); o[3] = f2b(a.w);
    o[4] = f2b(b.x); o[5] = f2b(b.y); o[6] = f2b(b.z); o[7] = f2b(b.w);
    return o;
}

constexpr float INV_M      = 0.17677669529663687f;   // 1/sqrt(32)
constexpr float INV_R      = 0.25f;                  // 1/sqrt(16)
constexpr float INV_H      = 0.125f;                 // 1/sqrt(64)
constexpr float INV_2M_DEG = 0.125f * 0.17677669529663687f; // 1/sqrt(64)*1/sqrt(32)
constexpr float INV_FAN    = 0.0625f;                // 1/sqrt(32*8)
constexpr float INV_SQRT3  = 0.5773502691896258f;

// ---------- Kernel A: MFMA linear_1 + histogram + agg zero-fill + k_out weight prep ----------
// (4-way grid split.) linear_1 result stored PACKED bf16: feat[node][chan] =
// {s, vx, vy, vz} (8B) so the edge kernel's per-slot gather is ONE dwordx2 per lane.
// count is sharded x4 ((d<<2)|(e&3)) to cut same-address atomic contention.
// Histogram now 4 edges/thread (625 blocks, was 2500) — same atomics, quarter the
// block scheduling overhead. Prep segment converts k_out's 40KB weight block to
// bf16 in ws (wsB) so k_out stages via coalesced int4 copy (measured ~10us, r7).
__global__ __launch_bounds__(256) void k_lin1h(
    const float* __restrict__ node_s, const float* __restrict__ node_v,
    const float* __restrict__ W1s, const float* __restrict__ W1v,
    short* __restrict__ feat, int N,
    const int* __restrict__ eidx, int* __restrict__ count, int E,
    float4* __restrict__ aggz, int nagg4, int nblin, int nbhist, int nbz,
    const float* __restrict__ W2s, const float* __restrict__ W2v,
    const float* __restrict__ Wscs, const float* __restrict__ Wscv,
    short* __restrict__ wsB)
{
    int b = blockIdx.x;
    int tid = threadIdx.x;
    if (b >= nblin + nbhist + nbz) {        // k_out weight prep: 20480 elems, 4/thread
        int i0 = (b - nblin - nbhist - nbz) * 1024 + tid;
        #pragma unroll
        for (int r = 0; r < 4; ++r) {
            int idx = i0 + r * 256;
            if (idx < 20480) {
                int f = idx >> 9, rem = idx & 511;
                int ln = rem >> 3, j = rem & 7;
                int qq = ln >> 4, lmm = ln & 15;
                const float* Wp; int nt, t; float sc;
                if (f < 4)       { Wp = W2s;  nt = f >> 1;              t = f & 1; sc = INV_2M_DEG; }
                else if (f < 8)  { int g = f - 4;  Wp = W2v;  nt = g >> 1; t = g & 1; sc = INV_2M_DEG; }
                else if (f < 24) { int g = f - 8;  Wp = Wscs; nt = g >> 3; t = g & 7; sc = INV_FAN; }
                else             { int g = f - 24; Wp = Wscv; nt = g >> 3; t = g & 7; sc = INV_FAN; }
                wsB[idx] = f2b(Wp[(t * 32 + qq * 8 + j) * 32 + nt * 16 + lmm] * sc);
            }
        }
        return;
    }
    if (b >= nblin + nbhist) {              // agg zero-fill: 1024 float4 per block
        int i0 = (b - nblin - nbhist) * 1024 + tid;
        #pragma unroll
        for (int r = 0; r < 4; ++r) {
            int idx = i0 + r * 256;
            if (idx < nagg4) aggz[idx] = make_float4(0.f, 0.f, 0.f, 0.f);
        }
        return;
    }
    if (b >= nblin) {                        // histogram (sharded x4), 4 edges/thread
        int e0 = (b - nblin) * 1024 + tid;
        #pragma unroll
        for (int r = 0; r < 4; ++r) {
            int e = e0 + r * 256;
            if (e < E) atomicAdd(&count[(eidx[E + e] << 2) | (e & 3)], 1);
        }
        return;
    }
    // stage W1s/W1v B-fragments: f=0,1 -> W1s nt=0,1 ; f=2,3 -> W1v nt=0,1
    __shared__ short sF[4 * 512];
    {
        int f = tid >> 6, ln = tid & 63;
        int q = ln >> 4, lm = ln & 15;
        int nt = f & 1;
        const float* Wp = (f < 2) ? W1s : W1v;
        short* d8 = &sF[tid * 8];
        #pragma unroll
        for (int j = 0; j < 8; ++j) {
            int k = q * 8 + j;
            d8[j] = f2b(Wp[k * 32 + nt * 16 + lm] * INV_M);
        }
    }
    __syncthreads();
    int lane = tid & 63, wv = tid >> 6;
    int q = lane >> 4, lm = lane & 15;
    int n0 = (b * 4 + wv) * 16;
    if (n0 >= N) return;                     // N = 20000 = 1250 tiles exactly
    int nr = n0 + lm;

    const float* nsp = node_s + (size_t)nr * 32;
    bf16x8 as8 = pack8(*(const float4*)(nsp + q * 8), *(const float4*)(nsp + q * 8 + 4));
    const float* nvp = node_v + (size_t)nr * 96;
    bf16x8 av8[3];
    #pragma unroll
    for (int i = 0; i < 3; ++i)
        #pragma unroll
        for (int j = 0; j < 8; ++j) av8[i][j] = f2b(nvp[(q * 8 + j) * 3 + i]);

    #pragma unroll
    for (int nt = 0; nt < 2; ++nt) {
        bf16x8 bs = *(const bf16x8*)&sF[(nt * 64 + lane) * 8];
        bf16x8 bv = *(const bf16x8*)&sF[((2 + nt) * 64 + lane) * 8];
        f32x4 sa = __builtin_amdgcn_mfma_f32_16x16x32_bf16(
            as8, bs, (f32x4){0.f, 0.f, 0.f, 0.f}, 0, 0, 0);
        f32x4 v0 = __builtin_amdgcn_mfma_f32_16x16x32_bf16(
            av8[0], bv, (f32x4){0.f, 0.f, 0.f, 0.f}, 0, 0, 0);
        f32x4 v1 = __builtin_amdgcn_mfma_f32_16x16x32_bf16(
            av8[1], bv, (f32x4){0.f, 0.f, 0.f, 0.f}, 0, 0, 0);
        f32x4 v2 = __builtin_amdgcn_mfma_f32_16x16x32_bf16(
            av8[2], bv, (f32x4){0.f, 0.f, 0.f, 0.f}, 0, 0, 0);
        #pragma unroll
        for (int r = 0; r < 4; ++r) {
            short4v o = {f2b(sa[r]), f2b(v0[r]), f2b(v1[r]), f2b(v2[r])};
            *(short4v*)&feat[(size_t)(n0 + q * 4 + r) * 128 + (nt * 16 + lm) * 4] = o;
        }
    }
}

// ---------------- hierarchical exclusive scan (2 kernels; B folded into C) ----------------
__global__ __launch_bounds__(256) void k_scanA(
    const int* __restrict__ count, int* __restrict__ bsum, int M)
{
    int tid = threadIdx.x;
    int i = blockIdx.x * 256 + tid;
    int v = (i < M) ? count[i] : 0;
    int x = v;
    #pragma unroll
    for (int off = 1; off < 64; off <<= 1) x += __shfl_xor(x, off, 64);
    __shared__ int ws[4];
    int lane = tid & 63, wv = tid >> 6;
    if (lane == 0) ws[wv] = x;
    __syncthreads();
    if (tid == 0) bsum[blockIdx.x] = ws[0] + ws[1] + ws[2] + ws[3];
}

// scanC: each block computes its own bsum-prefix (NB<=512: two strided loads + block
// reduce) then local exclusive scan -> cursor. Removes the separate k_scanB dispatch.
__global__ __launch_bounds__(256) void k_scanC(
    const int* __restrict__ count, const int* __restrict__ bsum,
    int* __restrict__ cursor, int M)
{
    int tid = threadIdx.x, bid = blockIdx.x;
    int lane = tid & 63, wv = tid >> 6;
    int p = 0;
    if (tid < bid) p = bsum[tid];
    if (tid + 256 < bid) p += bsum[tid + 256];
    #pragma unroll
    for (int off = 1; off < 64; off <<= 1) p += __shfl_xor(p, off, 64);
    __shared__ int rs[4];
    if (lane == 0) rs[wv] = p;
    __syncthreads();
    int boffv = rs[0] + rs[1] + rs[2] + rs[3];

    int i = bid * 256 + tid;
    int v = (i < M) ? count[i] : 0;
    int x = v;
    #pragma unroll
    for (int off = 1; off < 64; off <<= 1) {
        int y = __shfl_up(x, off, 64);
        if (lane >= off) x += y;
    }
    __shared__ int wsum[4];
    if (lane == 63) wsum[wv] = x;
    __syncthreads();
    int add = 0;
    #pragma unroll
    for (int w = 0; w < 3; ++w) if (w < wv) add += wsum[w];
    if (i < M) cursor[i] = x - v + add + boffv;
}

// CSR fill: single 8B packed {e, dst} scatter per edge, 4 edges/thread (625 blocks).
// r3-proven epair form — k_fused re-gathers src from eidx; those extra in-flight
// random loads measured FASTER than carrying src in epair (MLP-bound kernel, more
// outstanding requests = more achieved BW; r5/r6's removal cost +13us twice).
__global__ __launch_bounds__(256) void k_fill(
    const int* __restrict__ eidx, int* __restrict__ cursor,
    int2* __restrict__ epair, int E)
{
    int e0 = blockIdx.x * 1024 + threadIdx.x;
    #pragma unroll
    for (int r = 0; r < 4; ++r) {
        int e = e0 + r * 256;
        if (e < E) {
            int d = eidx[E + e];
            int slot = atomicAdd(&cursor[(d << 2) | (e & 3)], 1);
            epair[slot] = make_int2(e, d);
        }
    }
}

// ---------------- Fused: MFMA radial MLP + CG TP + segmented accumulate ----------------
// r3-PROVEN FORM (121.9-123.8us measured on two different containers at ~1640 GB/s
// achieved). DO NOT EDIT without an A/B: the kernel is bound by VALU issue +
// memory-level parallelism; r5/r6 (fewer outstanding loads), r7 (deeper ring,
// compiler sank it), r9 (volatile weight streaming) all measured neutral-to-worse.
// Per-slot source gather is ONE 8B load: feat[src][u] = {s, vx, vy, vz} bf16.
// (a) next-chunk {epair, emb, src, y1} all prefetched a chunk ahead,
// (b) first 8 feat gathers issued BEFORE the radial-MLP MFMA section, ring 8-deep
//     with mid-loop refill, (c) y0 == 1 elided; 1/sqrt3 applied at layer-2 write.
// NO waves-per-EU bound (r1: bound crushed VGPR to 64 -> spill). NOTE: wl/hl
// stores MUST stay short-element typed (TBAA; punned store miscompiled earlier).
__global__ __launch_bounds__(256) void k_fused(
    const float* __restrict__ emb, const int2* __restrict__ epair,
    const int* __restrict__ eidx,
    const float* __restrict__ y1,
    const float* __restrict__ Wr1, const float* __restrict__ Wr2,
    const short* __restrict__ feat,
    float* __restrict__ agg_s, float* __restrict__ agg_v, int E)
{
    __shared__ short sW1[4 * 512];          // layer1 B frags (4 KB)
    __shared__ short hbuf[4][16 * 72];      // per-wave h tile [m][hid]
    __shared__ short wtl[4][2 * 64 * 18];   // per-wave w tiles [A|B][c'][m]

    int tid = threadIdx.x;
    {   // stage Wr1 fragments (K padded 16->32 with zeros)
        int f = tid >> 6, ln = tid & 63;
        int qq = ln >> 4, lmm = ln & 15;
        short* d8 = &sW1[(f * 64 + ln) * 8];
        #pragma unroll
        for (int j = 0; j < 8; ++j) {
            int k = qq * 8 + j;
            d8[j] = (k < 16) ? f2b(Wr1[k * 64 + f * 16 + lmm] * INV_R) : (short)0;
        }
    }
    __syncthreads();

    int lane = tid & 63, wv = tid >> 6;
    int q = lane >> 4, lm = lane & 15;
    int u = lane & 31;
    bool low = (lane < 32);

    // Wr2 fragments in VGPRs
    bf16x8 wr2f[16];
    #pragma unroll
    for (int nt = 0; nt < 8; ++nt) {
        #pragma unroll
        for (int kc = 0; kc < 2; ++kc) {
            #pragma unroll
            for (int j = 0; j < 8; ++j) {
                int k = kc * 32 + q * 8 + j;
                wr2f[nt * 2 + kc][j] = f2b(Wr2[k * 128 + nt * 16 + lm] * INV_H);
            }
        }
    }

    short* hl = hbuf[wv];
    short* wl = wtl[wv];

    int base = blockIdx.x * 256 + wv * 64;
    if (base >= E) return;

    // chunk-0 prefetch (E = 2500*256 exactly, no bounds handling needed)
    int2 nep = epair[base + lm];
    float4 pa = make_float4(0.f, 0.f, 0.f, 0.f);
    float4 pb = make_float4(0.f, 0.f, 0.f, 0.f);
    if (q < 2) {
        const float* ep = emb + (size_t)nep.x * 16 + q * 8;
        pa = *(const float4*)ep;
        pb = *(const float4*)(ep + 4);
    }
    int nsrc = 0;
    if (lane >= 16 && lane < 32) nsrc = eidx[nep.x];
    float npk = (q < 3) ? y1[(size_t)nep.x * 3 + q] : 0.f;

    float accs = 0.f, acc0 = 0.f, acc1 = 0.f, acc2 = 0.f;
    int cur = -1;

    for (int ch = 0; ch < 4; ++ch) {
        int2 myep = nep;
        int meta = (lane < 16) ? myep.y : nsrc;
        float pkm = npk;

        bf16x8 af = (bf16x8){0, 0, 0, 0, 0, 0, 0, 0};
        if (q < 2) af = pack8(pa, pb);

        // issue first-8 feat gathers NOW — latency hides under the MLP MFMAs below
        short4v pg[8];
        #pragma unroll
        for (int k = 0; k < 8; ++k) {
            int sr = rlanei(meta, 16 + k);
            pg[k] = *(const short4v*)&feat[(size_t)sr * 128 + u * 4];
        }

        // prefetch everything for chunk ch+1
        if (ch < 3) {
            nep = epair[base + ch * 16 + 16 + lm];
            if (q < 2) {
                const float* ep = emb + (size_t)nep.x * 16 + q * 8;
                pa = *(const float4*)ep;
                pb = *(const float4*)(ep + 4);
            }
            if (lane >= 16 && lane < 32) nsrc = eidx[nep.x];
            npk = (q < 3) ? y1[(size_t)nep.x * 3 + q] : 0.f;
        }

        // ---- layer 1: 4 MFMA -> hbuf ----
        #pragma unroll
        for (int nt = 0; nt < 4; ++nt) {
            bf16x8 bfr = *(const bf16x8*)&sW1[(nt * 64 + lane) * 8];
            f32x4 x = __builtin_amdgcn_mfma_f32_16x16x32_bf16(
                af, bfr, (f32x4){0.f, 0.f, 0.f, 0.f}, 0, 0, 0);
            #pragma unroll
            for (int r = 0; r < 4; ++r)
                hl[(q * 4 + r) * 72 + nt * 16 + lm] = f2b(sspf(x[r]));
        }

        // ---- layer 2: 16 MFMA -> permuted w tile (1/sqrt3 folded into w4 cols) ----
        bf16x8 ha = *(const bf16x8*)&hl[lm * 72 + q * 8];
        bf16x8 hb = *(const bf16x8*)&hl[lm * 72 + 32 + q * 8];
        #pragma unroll
        for (int nt = 0; nt < 8; ++nt) {
            f32x4 acc = __builtin_amdgcn_mfma_f32_16x16x32_bf16(
                ha, wr2f[nt * 2], (f32x4){0.f, 0.f, 0.f, 0.f}, 0, 0, 0);
            acc = __builtin_amdgcn_mfma_f32_16x16x32_bf16(hb, wr2f[nt * 2 + 1], acc, 0, 0, 0);
            float scl = (nt >= 6) ? INV_SQRT3 : 1.0f;   // nt>=6 == w4 columns
            int cp = (nt & 1) * 16 + lm + ((nt >> 2) & 1) * 32;
            int half = (nt >> 1) & 1;
            short* wp = &wl[half * 1152 + cp * 18 + q * 4];
            short2v p01 = {f2b(acc[0] * scl), f2b(acc[1] * scl)};
            short2v p23 = {f2b(acc[2] * scl), f2b(acc[3] * scl)};
            *(short2v*)&wp[0] = p01;
            *(short2v*)&wp[2] = p23;
        }

        // ---- TP + segmented accumulation, 8-deep single-load gather pipeline ----
        #pragma unroll
        for (int i = 0; i < 16; ++i) {
            short4v g = pg[i & 7];
            if (i + 8 < 16) {
                int sr = rlanei(meta, 16 + i + 8);
                pg[(i + 8) & 7] = *(const short4v*)&feat[(size_t)sr * 128 + u * 4];
            }
            float se = b2f(g[0]), vx = b2f(g[1]), vy = b2f(g[2]), vz = b2f(g[3]);
            int d = rlanei(meta, i);
            if (d != cur) {
                if (cur >= 0) {
                    atomicAdd(&agg_s[(size_t)cur * 64 + lane], accs);
                    float* av = &agg_v[(size_t)cur * 192 + lane];
                    atomicAdd(av, acc0); atomicAdd(av + 64, acc1); atomicAdd(av + 128, acc2);
                }
                accs = acc0 = acc1 = acc2 = 0.f;
                cur = d;
            }
            float la = b2f(wl[lane * 18 + i]);
            float lb = b2f(wl[1152 + lane * 18 + i]);
            float y1x = rlanef(pkm, i);
            float y1y = rlanef(pkm, 16 + i);
            float y1z = rlanef(pkm, 32 + i);
            float dot = vx * y1x + vy * y1y + vz * y1z;
            accs = fmaf(low ? la : lb, low ? se : dot, accs);
            float t = low ? lb * se : la;
            acc0 = fmaf(t, low ? y1x : vx, acc0);
            acc1 = fmaf(t, low ? y1y : vy, acc1);
            acc2 = fmaf(t, low ? y1z : vz, acc2);
        }
    }
    if (cur >= 0) {
        atomicAdd(&agg_s[(size_t)cur * 64 + lane], accs);
        float* av = &agg_v[(size_t)cur * 192 + lane];
        atomicAdd(av, acc0); atomicAdd(av + 64, acc1); atomicAdd(av + 128, acc2);
    }
}

// ---------------- Kernel C: MFMA linear_2 + self-connection + output ----------------
// Weights pre-converted to bf16 in wsB; staging is a coalesced int4 copy.
// 8 tiles/block (157 blocks, was 313): all blocks fit one residency wave, weights
// staged once per block instead of 1.2x; g-loop unroll(1) to hold VGPR flat.
__global__ __launch_bounds__(256) void k_out(
    const float* __restrict__ node_s, const float* __restrict__ node_v,
    const float* __restrict__ attrs,
    const float* __restrict__ agg_s, const float* __restrict__ agg_v,
    const short* __restrict__ wsB,
    float* __restrict__ out, int N)
{
    __shared__ int4 sB4[2560];   // 40 KB
    int tid = threadIdx.x;
    {
        const int4* gw = (const int4*)wsB;
        for (int i = tid; i < 2560; i += 256) sB4[i] = gw[i];
    }
    __syncthreads();
    const short* sB = (const short*)sB4;

    int lane = tid & 63, wv = tid >> 6;
    int q = lane >> 4, lm = lane & 15;

    #pragma unroll 1
    for (int g = 0; g < 2; ++g) {
        int n0 = (blockIdx.x * 8 + wv + g * 4) * 16;
        if (n0 >= N) continue;
        int nr = n0 + lm;

        float4 at0 = *(const float4*)(attrs + (size_t)nr * 8);
        float4 at1 = *(const float4*)(attrs + (size_t)nr * 8 + 4);
        float at[8] = {at0.x, at0.y, at0.z, at0.w, at1.x, at1.y, at1.z, at1.w};

        const float* asp = agg_s + (size_t)nr * 64;
        bf16x8 aS[2];
        #pragma unroll
        for (int kc = 0; kc < 2; ++kc)
            aS[kc] = pack8(*(const float4*)(asp + kc * 32 + q * 8),
                           *(const float4*)(asp + kc * 32 + q * 8 + 4));

        const float* nsp = node_s + (size_t)nr * 32;
        bf16x8 scs[8];
        #pragma unroll
        for (int t = 0; t < 8; ++t) {
            float nv_ = nsp[t * 4 + q];
            #pragma unroll
            for (int j = 0; j < 8; ++j) scs[t][j] = f2b(nv_ * at[j]);
        }

        #pragma unroll
        for (int nt = 0; nt < 2; ++nt) {
            f32x4 acc = (f32x4){0.f, 0.f, 0.f, 0.f};
            acc = __builtin_amdgcn_mfma_f32_16x16x32_bf16(
                aS[0], *(const bf16x8*)&sB[(nt * 2 + 0) * 512 + lane * 8], acc, 0, 0, 0);
            acc = __builtin_amdgcn_mfma_f32_16x16x32_bf16(
                aS[1], *(const bf16x8*)&sB[(nt * 2 + 1) * 512 + lane * 8], acc, 0, 0, 0);
            #pragma unroll
            for (int t = 0; t < 8; ++t)
                acc = __builtin_amdgcn_mfma_f32_16x16x32_bf16(
                    scs[t], *(const bf16x8*)&sB[(8 + nt * 8 + t) * 512 + lane * 8], acc, 0, 0, 0);
            #pragma unroll
            for (int r = 0; r < 4; ++r)
                out[(size_t)(n0 + q * 4 + r) * 128 + nt * 16 + lm] = acc[r];
        }

        const float* nvp = node_v + (size_t)nr * 96;
        const float* avp = agg_v + (size_t)nr * 192;
        #pragma unroll
        for (int i = 0; i < 3; ++i) {
            bf16x8 aV[2];
            #pragma unroll
            for (int kc = 0; kc < 2; ++kc)
                aV[kc] = pack8(*(const float4*)(avp + i * 64 + kc * 32 + q * 8),
                               *(const float4*)(avp + i * 64 + kc * 32 + q * 8 + 4));
            bf16x8 scv[8];
            #pragma unroll
            for (int t = 0; t < 8; ++t) {
                float nv_ = nvp[(t * 4 + q) * 3 + i];
                #pragma unroll
                for (int j = 0; j < 8; ++j) scv[t][j] = f2b(nv_ * at[j]);
            }
            #pragma unroll
            for (int nt = 0; nt < 2; ++nt) {
                f32x4 acc = (f32x4){0.f, 0.f, 0.f, 0.f};
                acc = __builtin_amdgcn_mfma_f32_16x16x32_bf16(
                    aV[0], *(const bf16x8*)&sB[(4 + nt * 2 + 0) * 512 + lane * 8], acc, 0, 0, 0);
                acc = __builtin_amdgcn_mfma_f32_16x16x32_bf16(
                    aV[1], *(const bf16x8*)&sB[(4 + nt * 2 + 1) * 512 + lane * 8], acc, 0, 0, 0);
                #pragma unroll
                for (int t = 0; t < 8; ++t)
                    acc = __builtin_amdgcn_mfma_f32_16x16x32_bf16(
                        scv[t], *(const bf16x8*)&sB[(24 + nt * 8 + t) * 512 + lane * 8], acc, 0, 0, 0);
                #pragma unroll
                for (int r = 0; r < 4; ++r)
                    out[(size_t)(n0 + q * 4 + r) * 128 + 32 + (nt * 16 + lm) * 3 + i] = acc[r];
            }
        }
    }
}

extern "C" void kernel_launch(void* const* d_in, const int* in_sizes, int n_in,
                              void* d_out, int out_size, void* d_ws, size_t ws_size,
                              hipStream_t stream)
{
    const float* node_s = (const float*)d_in[0];
    const float* node_v = (const float*)d_in[1];
    const float* attrs  = (const float*)d_in[2];
    const float* emb    = (const float*)d_in[3];
    const float* y1     = (const float*)d_in[5];
    const int*   eidx   = (const int*)d_in[6];
    const float* W1s  = (const float*)d_in[7];
    const float* W1v  = (const float*)d_in[8];
    const float* Wr1  = (const float*)d_in[9];
    const float* Wr2  = (const float*)d_in[10];
    const float* W2s  = (const float*)d_in[11];
    const float* W2v  = (const float*)d_in[12];
    const float* Wscs = (const float*)d_in[13];
    const float* Wscv = (const float*)d_in[14];

    int N = in_sizes[0] / 32;   // 20000
    int E = in_sizes[3] / 16;   // 640000

    float* agg_s = (float*)d_ws;                       // N*64
    float* agg_v = agg_s + (size_t)N * 64;             // N*192
    short* feat  = (short*)(agg_v + (size_t)N * 192);  // N*128 bf16 (packed {s,vx,vy,vz})
    int* count   = (int*)(feat + (size_t)N * 128);     // 4N (sharded)
    int* cursor  = count + (size_t)4 * N;              // 4N
    int2* epair  = (int2*)(cursor + (size_t)4 * N);    // E (8B: e, dst)
    int* bsum    = (int*)(epair + E);                  // scan block sums (1024)
    short* wsB   = (short*)(bsum + 1024);              // k_out weights, 20480 bf16 (40KB)

    (void)hipMemsetAsync(count, 0, (size_t)4 * N * sizeof(int), stream);

    int M  = 4 * N;                          // sharded count length (80000)
    int NB = (M + 255) / 256;                // scan blocks (313)
    int nblin  = (N + 63) / 64;              // 64 nodes (4 wave-tiles) per block
    int nbhist = (E + 1023) / 1024;          // histogram: 4 edges/thread (625)
    int nagg4  = N * 64;                     // N*256 floats / 4
    int nbz    = (nagg4 + 1023) / 1024;
    int nbw    = (20480 + 1023) / 1024;      // k_out weight prep (20 blocks)
    k_lin1h<<<dim3(nblin + nbhist + nbz + nbw), dim3(256), 0, stream>>>(
        node_s, node_v, W1s, W1v, feat, N,
        eidx, count, E, (float4*)agg_s, nagg4, nblin, nbhist, nbz,
        W2s, W2v, Wscs, Wscv, wsB);
    k_scanA<<<dim3(NB), dim3(256), 0, stream>>>(count, bsum, M);
    k_scanC<<<dim3(NB), dim3(256), 0, stream>>>(count, bsum, cursor, M);
    k_fill<<<dim3((E + 1023) / 1024), dim3(256), 0, stream>>>(eidx, cursor, epair, E);
    k_fused<<<dim3((E + 255) / 256), dim3(256), 0, stream>>>(emb, epair, eidx, y1,
                                                             Wr1, Wr2, feat,
                                                             agg_s, agg_v, E);
    k_out<<<dim3((N + 127) / 128), dim3(256), 0, stream>>>(node_s, node_v, attrs, agg_s, agg_v,
                                                           wsB, (float*)d_out, N);
}

// Round 12
// 308.871 us; speedup vs baseline: 1.0627x; 1.0627x over previous
//
#include <hip/hip_runtime.h>
#include <math.h>

typedef short bf16x8 __attribute__((ext_vector_type(8)));
typedef short short2v __attribute__((ext_vector_type(2)));
typedef short short4v __attribute__((ext_vector_type(4)));
typedef float f32x4 __attribute__((ext_vector_type(4)));

__device__ __forceinline__ float sspf(float x) {
    return __logf(1.0f + __expf(x)) - 0.6931471805599453f;
}
__device__ __forceinline__ short f2b(float f) {
    union { float f; unsigned u; } c; c.f = f;
    unsigned r = c.u + 0x7fff + ((c.u >> 16) & 1);
    return (short)(r >> 16);
}
__device__ __forceinline__ float b2f(short s) {
    union { unsigned u; float f; } c; c.u = ((unsigned)(unsigned short)s) << 16;
    return c.f;
}
__device__ __forceinline__ int rlanei(int v, int l) {
    return __builtin_amdgcn_readlane(v, l);
}
__device__ __forceinline__ float rlanef(float v, int l) {
    return __uint_as_float(__builtin_amdgcn_readlane(__float_as_uint(v), l));
}
__device__ __forceinline__ bf16x8 pack8(float4 a, float4 b) {
    bf16x8 o;
    o[0] = f2b(a.x); o[1] = f2b(a.y); o[2] = f2b(a.z); o[3] = f2b(a.w);
    o[4] = f2b(b.x); o[5] = f2b(b.y); o[6] = f2b(b.z); o[7] = f2b(b.w);
    return o;
}

constexpr float INV_M      = 0.17677669529663687f;   // 1/sqrt(32)
constexpr float INV_R      = 0.25f;                  // 1/sqrt(16)
constexpr float INV_H      = 0.125f;                 // 1/sqrt(64)
constexpr float INV_2M_DEG = 0.125f * 0.17677669529663687f; // 1/sqrt(64)*1/sqrt(32)
constexpr float INV_FAN    = 0.0625f;                // 1/sqrt(32*8)
constexpr float INV_SQRT3  = 0.5773502691896258f;

// ---------- Kernel A: MFMA linear_1 + histogram + agg zero-fill + k_out weight prep ----------
// (4-way grid split.) linear_1 result stored PACKED bf16: feat[node][chan] =
// {s, vx, vy, vz} (8B) so the edge kernel's per-slot gather is ONE dwordx2 per lane.
// count is sharded x4 ((d<<2)|(e&3)) to cut same-address atomic contention.
// Histogram 4 edges/thread is SAFE (atomic counts are order-independent).
// Prep segment converts k_out's 40KB weight block to bf16 in ws (wsB).
__global__ __launch_bounds__(256) void k_lin1h(
    const float* __restrict__ node_s, const float* __restrict__ node_v,
    const float* __restrict__ W1s, const float* __restrict__ W1v,
    short* __restrict__ feat, int N,
    const int* __restrict__ eidx, int* __restrict__ count, int E,
    float4* __restrict__ aggz, int nagg4, int nblin, int nbhist, int nbz,
    const float* __restrict__ W2s, const float* __restrict__ W2v,
    const float* __restrict__ Wscs, const float* __restrict__ Wscv,
    short* __restrict__ wsB)
{
    int b = blockIdx.x;
    int tid = threadIdx.x;
    if (b >= nblin + nbhist + nbz) {        // k_out weight prep: 20480 elems, 4/thread
        int i0 = (b - nblin - nbhist - nbz) * 1024 + tid;
        #pragma unroll
        for (int r = 0; r < 4; ++r) {
            int idx = i0 + r * 256;
            if (idx < 20480) {
                int f = idx >> 9, rem = idx & 511;
                int ln = rem >> 3, j = rem & 7;
                int qq = ln >> 4, lmm = ln & 15;
                const float* Wp; int nt, t; float sc;
                if (f < 4)       { Wp = W2s;  nt = f >> 1;              t = f & 1; sc = INV_2M_DEG; }
                else if (f < 8)  { int g = f - 4;  Wp = W2v;  nt = g >> 1; t = g & 1; sc = INV_2M_DEG; }
                else if (f < 24) { int g = f - 8;  Wp = Wscs; nt = g >> 3; t = g & 7; sc = INV_FAN; }
                else             { int g = f - 24; Wp = Wscv; nt = g >> 3; t = g & 7; sc = INV_FAN; }
                wsB[idx] = f2b(Wp[(t * 32 + qq * 8 + j) * 32 + nt * 16 + lmm] * sc);
            }
        }
        return;
    }
    if (b >= nblin + nbhist) {              // agg zero-fill: 1024 float4 per block
        int i0 = (b - nblin - nbhist) * 1024 + tid;
        #pragma unroll
        for (int r = 0; r < 4; ++r) {
            int idx = i0 + r * 256;
            if (idx < nagg4) aggz[idx] = make_float4(0.f, 0.f, 0.f, 0.f);
        }
        return;
    }
    if (b >= nblin) {                        // histogram (sharded x4), 4 edges/thread
        int e0 = (b - nblin) * 1024 + tid;
        #pragma unroll
        for (int r = 0; r < 4; ++r) {
            int e = e0 + r * 256;
            if (e < E) atomicAdd(&count[(eidx[E + e] << 2) | (e & 3)], 1);
        }
        return;
    }
    // stage W1s/W1v B-fragments: f=0,1 -> W1s nt=0,1 ; f=2,3 -> W1v nt=0,1
    __shared__ short sF[4 * 512];
    {
        int f = tid >> 6, ln = tid & 63;
        int q = ln >> 4, lm = ln & 15;
        int nt = f & 1;
        const float* Wp = (f < 2) ? W1s : W1v;
        short* d8 = &sF[tid * 8];
        #pragma unroll
        for (int j = 0; j < 8; ++j) {
            int k = q * 8 + j;
            d8[j] = f2b(Wp[k * 32 + nt * 16 + lm] * INV_M);
        }
    }
    __syncthreads();
    int lane = tid & 63, wv = tid >> 6;
    int q = lane >> 4, lm = lane & 15;
    int n0 = (b * 4 + wv) * 16;
    if (n0 >= N) return;                     // N = 20000 = 1250 tiles exactly
    int nr = n0 + lm;

    const float* nsp = node_s + (size_t)nr * 32;
    bf16x8 as8 = pack8(*(const float4*)(nsp + q * 8), *(const float4*)(nsp + q * 8 + 4));
    const float* nvp = node_v + (size_t)nr * 96;
    bf16x8 av8[3];
    #pragma unroll
    for (int i = 0; i < 3; ++i)
        #pragma unroll
        for (int j = 0; j < 8; ++j) av8[i][j] = f2b(nvp[(q * 8 + j) * 3 + i]);

    #pragma unroll
    for (int nt = 0; nt < 2; ++nt) {
        bf16x8 bs = *(const bf16x8*)&sF[(nt * 64 + lane) * 8];
        bf16x8 bv = *(const bf16x8*)&sF[((2 + nt) * 64 + lane) * 8];
        f32x4 sa = __builtin_amdgcn_mfma_f32_16x16x32_bf16(
            as8, bs, (f32x4){0.f, 0.f, 0.f, 0.f}, 0, 0, 0);
        f32x4 v0 = __builtin_amdgcn_mfma_f32_16x16x32_bf16(
            av8[0], bv, (f32x4){0.f, 0.f, 0.f, 0.f}, 0, 0, 0);
        f32x4 v1 = __builtin_amdgcn_mfma_f32_16x16x32_bf16(
            av8[1], bv, (f32x4){0.f, 0.f, 0.f, 0.f}, 0, 0, 0);
        f32x4 v2 = __builtin_amdgcn_mfma_f32_16x16x32_bf16(
            av8[2], bv, (f32x4){0.f, 0.f, 0.f, 0.f}, 0, 0, 0);
        #pragma unroll
        for (int r = 0; r < 4; ++r) {
            short4v o = {f2b(sa[r]), f2b(v0[r]), f2b(v1[r]), f2b(v2[r])};
            *(short4v*)&feat[(size_t)(n0 + q * 4 + r) * 128 + (nt * 16 + lm) * 4] = o;
        }
    }
}

// ---------------- hierarchical exclusive scan (2 kernels; B folded into C) ----------------
__global__ __launch_bounds__(256) void k_scanA(
    const int* __restrict__ count, int* __restrict__ bsum, int M)
{
    int tid = threadIdx.x;
    int i = blockIdx.x * 256 + tid;
    int v = (i < M) ? count[i] : 0;
    int x = v;
    #pragma unroll
    for (int off = 1; off < 64; off <<= 1) x += __shfl_xor(x, off, 64);
    __shared__ int ws[4];
    int lane = tid & 63, wv = tid >> 6;
    if (lane == 0) ws[wv] = x;
    __syncthreads();
    if (tid == 0) bsum[blockIdx.x] = ws[0] + ws[1] + ws[2] + ws[3];
}

// scanC: each block computes its own bsum-prefix (NB<=512: two strided loads + block
// reduce) then local exclusive scan -> cursor. Removes the separate k_scanB dispatch.
__global__ __launch_bounds__(256) void k_scanC(
    const int* __restrict__ count, const int* __restrict__ bsum,
    int* __restrict__ cursor, int M)
{
    int tid = threadIdx.x, bid = blockIdx.x;
    int lane = tid & 63, wv = tid >> 6;
    int p = 0;
    if (tid < bid) p = bsum[tid];
    if (tid + 256 < bid) p += bsum[tid + 256];
    #pragma unroll
    for (int off = 1; off < 64; off <<= 1) p += __shfl_xor(p, off, 64);
    __shared__ int rs[4];
    if (lane == 0) rs[wv] = p;
    __syncthreads();
    int boffv = rs[0] + rs[1] + rs[2] + rs[3];

    int i = bid * 256 + tid;
    int v = (i < M) ? count[i] : 0;
    int x = v;
    #pragma unroll
    for (int off = 1; off < 64; off <<= 1) {
        int y = __shfl_up(x, off, 64);
        if (lane >= off) x += y;
    }
    __shared__ int wsum[4];
    if (lane == 63) wsum[wv] = x;
    __syncthreads();
    int add = 0;
    #pragma unroll
    for (int w = 0; w < 3; ++w) if (w < wv) add += wsum[w];
    if (i < M) cursor[i] = x - v + add + boffv;
}

// CSR fill: single 8B packed {e, dst} scatter per edge. ONE EDGE PER THREAD —
// r11 lesson: 4-edges/thread strided insertion scrambles each dst-segment's
// e-ordering (consecutive slots ~256 apart -> emb rows ~16KB apart), costing
// k_fused 122->149us (achieved BW 1640->1350 GB/s, FETCH unchanged). epair
// insertion order is a LOAD-BEARING locality property; do not batch this kernel.
__global__ __launch_bounds__(256) void k_fill(
    const int* __restrict__ eidx, int* __restrict__ cursor,
    int2* __restrict__ epair, int E)
{
    int e = blockIdx.x * 256 + threadIdx.x;
    if (e < E) {
        int d = eidx[E + e];
        int slot = atomicAdd(&cursor[(d << 2) | (e & 3)], 1);
        epair[slot] = make_int2(e, d);
    }
}

// ---------------- Fused: MFMA radial MLP + CG TP + segmented accumulate ----------------
// r3-PROVEN FORM (121.9-123.8us on two different containers at ~1640 GB/s
// achieved). DO NOT EDIT without an A/B: the kernel is bound by VALU issue +
// memory-level parallelism; r5/r6 (fewer outstanding loads), r7 (deeper ring,
// compiler sank it), r9 (volatile weight streaming) all measured neutral-to-worse;
// r11 (upstream epair reorder) cost 27us without touching this source.
// Per-slot source gather is ONE 8B load: feat[src][u] = {s, vx, vy, vz} bf16.
// (a) next-chunk {epair, emb, src, y1} all prefetched a chunk ahead,
// (b) first 8 feat gathers issued BEFORE the radial-MLP MFMA section, ring 8-deep
//     with mid-loop refill, (c) y0 == 1 elided; 1/sqrt3 applied at layer-2 write.
// NO waves-per-EU bound (r1: bound crushed VGPR to 64 -> spill). NOTE: wl/hl
// stores MUST stay short-element typed (TBAA; punned store miscompiled earlier).
__global__ __launch_bounds__(256) void k_fused(
    const float* __restrict__ emb, const int2* __restrict__ epair,
    const int* __restrict__ eidx,
    const float* __restrict__ y1,
    const float* __restrict__ Wr1, const float* __restrict__ Wr2,
    const short* __restrict__ feat,
    float* __restrict__ agg_s, float* __restrict__ agg_v, int E)
{
    __shared__ short sW1[4 * 512];          // layer1 B frags (4 KB)
    __shared__ short hbuf[4][16 * 72];      // per-wave h tile [m][hid]
    __shared__ short wtl[4][2 * 64 * 18];   // per-wave w tiles [A|B][c'][m]

    int tid = threadIdx.x;
    {   // stage Wr1 fragments (K padded 16->32 with zeros)
        int f = tid >> 6, ln = tid & 63;
        int qq = ln >> 4, lmm = ln & 15;
        short* d8 = &sW1[(f * 64 + ln) * 8];
        #pragma unroll
        for (int j = 0; j < 8; ++j) {
            int k = qq * 8 + j;
            d8[j] = (k < 16) ? f2b(Wr1[k * 64 + f * 16 + lmm] * INV_R) : (short)0;
        }
    }
    __syncthreads();

    int lane = tid & 63, wv = tid >> 6;
    int q = lane >> 4, lm = lane & 15;
    int u = lane & 31;
    bool low = (lane < 32);

    // Wr2 fragments in VGPRs
    bf16x8 wr2f[16];
    #pragma unroll
    for (int nt = 0; nt < 8; ++nt) {
        #pragma unroll
        for (int kc = 0; kc < 2; ++kc) {
            #pragma unroll
            for (int j = 0; j < 8; ++j) {
                int k = kc * 32 + q * 8 + j;
                wr2f[nt * 2 + kc][j] = f2b(Wr2[k * 128 + nt * 16 + lm] * INV_H);
            }
        }
    }

    short* hl = hbuf[wv];
    short* wl = wtl[wv];

    int base = blockIdx.x * 256 + wv * 64;
    if (base >= E) return;

    // chunk-0 prefetch (E = 2500*256 exactly, no bounds handling needed)
    int2 nep = epair[base + lm];
    float4 pa = make_float4(0.f, 0.f, 0.f, 0.f);
    float4 pb = make_float4(0.f, 0.f, 0.f, 0.f);
    if (q < 2) {
        const float* ep = emb + (size_t)nep.x * 16 + q * 8;
        pa = *(const float4*)ep;
        pb = *(const float4*)(ep + 4);
    }
    int nsrc = 0;
    if (lane >= 16 && lane < 32) nsrc = eidx[nep.x];
    float npk = (q < 3) ? y1[(size_t)nep.x * 3 + q] : 0.f;

    float accs = 0.f, acc0 = 0.f, acc1 = 0.f, acc2 = 0.f;
    int cur = -1;

    for (int ch = 0; ch < 4; ++ch) {
        int2 myep = nep;
        int meta = (lane < 16) ? myep.y : nsrc;
        float pkm = npk;

        bf16x8 af = (bf16x8){0, 0, 0, 0, 0, 0, 0, 0};
        if (q < 2) af = pack8(pa, pb);

        // issue first-8 feat gathers NOW — latency hides under the MLP MFMAs below
        short4v pg[8];
        #pragma unroll
        for (int k = 0; k < 8; ++k) {
            int sr = rlanei(meta, 16 + k);
            pg[k] = *(const short4v*)&feat[(size_t)sr * 128 + u * 4];
        }

        // prefetch everything for chunk ch+1
        if (ch < 3) {
            nep = epair[base + ch * 16 + 16 + lm];
            if (q < 2) {
                const float* ep = emb + (size_t)nep.x * 16 + q * 8;
                pa = *(const float4*)ep;
                pb = *(const float4*)(ep + 4);
            }
            if (lane >= 16 && lane < 32) nsrc = eidx[nep.x];
            npk = (q < 3) ? y1[(size_t)nep.x * 3 + q] : 0.f;
        }

        // ---- layer 1: 4 MFMA -> hbuf ----
        #pragma unroll
        for (int nt = 0; nt < 4; ++nt) {
            bf16x8 bfr = *(const bf16x8*)&sW1[(nt * 64 + lane) * 8];
            f32x4 x = __builtin_amdgcn_mfma_f32_16x16x32_bf16(
                af, bfr, (f32x4){0.f, 0.f, 0.f, 0.f}, 0, 0, 0);
            #pragma unroll
            for (int r = 0; r < 4; ++r)
                hl[(q * 4 + r) * 72 + nt * 16 + lm] = f2b(sspf(x[r]));
        }

        // ---- layer 2: 16 MFMA -> permuted w tile (1/sqrt3 folded into w4 cols) ----
        bf16x8 ha = *(const bf16x8*)&hl[lm * 72 + q * 8];
        bf16x8 hb = *(const bf16x8*)&hl[lm * 72 + 32 + q * 8];
        #pragma unroll
        for (int nt = 0; nt < 8; ++nt) {
            f32x4 acc = __builtin_amdgcn_mfma_f32_16x16x32_bf16(
                ha, wr2f[nt * 2], (f32x4){0.f, 0.f, 0.f, 0.f}, 0, 0, 0);
            acc = __builtin_amdgcn_mfma_f32_16x16x32_bf16(hb, wr2f[nt * 2 + 1], acc, 0, 0, 0);
            float scl = (nt >= 6) ? INV_SQRT3 : 1.0f;   // nt>=6 == w4 columns
            int cp = (nt & 1) * 16 + lm + ((nt >> 2) & 1) * 32;
            int half = (nt >> 1) & 1;
            short* wp = &wl[half * 1152 + cp * 18 + q * 4];
            short2v p01 = {f2b(acc[0] * scl), f2b(acc[1] * scl)};
            short2v p23 = {f2b(acc[2] * scl), f2b(acc[3] * scl)};
            *(short2v*)&wp[0] = p01;
            *(short2v*)&wp[2] = p23;
        }

        // ---- TP + segmented accumulation, 8-deep single-load gather pipeline ----
        #pragma unroll
        for (int i = 0; i < 16; ++i) {
            short4v g = pg[i & 7];
            if (i + 8 < 16) {
                int sr = rlanei(meta, 16 + i + 8);
                pg[(i + 8) & 7] = *(const short4v*)&feat[(size_t)sr * 128 + u * 4];
            }
            float se = b2f(g[0]), vx = b2f(g[1]), vy = b2f(g[2]), vz = b2f(g[3]);
            int d = rlanei(meta, i);
            if (d != cur) {
                if (cur >= 0) {
                    atomicAdd(&agg_s[(size_t)cur * 64 + lane], accs);
                    float* av = &agg_v[(size_t)cur * 192 + lane];
                    atomicAdd(av, acc0); atomicAdd(av + 64, acc1); atomicAdd(av + 128, acc2);
                }
                accs = acc0 = acc1 = acc2 = 0.f;
                cur = d;
            }
            float la = b2f(wl[lane * 18 + i]);
            float lb = b2f(wl[1152 + lane * 18 + i]);
            float y1x = rlanef(pkm, i);
            float y1y = rlanef(pkm, 16 + i);
            float y1z = rlanef(pkm, 32 + i);
            float dot = vx * y1x + vy * y1y + vz * y1z;
            accs = fmaf(low ? la : lb, low ? se : dot, accs);
            float t = low ? lb * se : la;
            acc0 = fmaf(t, low ? y1x : vx, acc0);
            acc1 = fmaf(t, low ? y1y : vy, acc1);
            acc2 = fmaf(t, low ? y1z : vz, acc2);
        }
    }
    if (cur >= 0) {
        atomicAdd(&agg_s[(size_t)cur * 64 + lane], accs);
        float* av = &agg_v[(size_t)cur * 192 + lane];
        atomicAdd(av, acc0); atomicAdd(av + 64, acc1); atomicAdd(av + 128, acc2);
    }
}

// ---------------- Kernel C: MFMA linear_2 + self-connection + output ----------------
// Weights pre-converted to bf16 in wsB; staging is a coalesced int4 copy.
// 8 tiles/block (157 blocks): weights staged once per block; g-loop unroll(1).
__global__ __launch_bounds__(256) void k_out(
    const float* __restrict__ node_s, const float* __restrict__ node_v,
    const float* __restrict__ attrs,
    const float* __restrict__ agg_s, const float* __restrict__ agg_v,
    const short* __restrict__ wsB,
    float* __restrict__ out, int N)
{
    __shared__ int4 sB4[2560];   // 40 KB
    int tid = threadIdx.x;
    {
        const int4* gw = (const int4*)wsB;
        for (int i = tid; i < 2560; i += 256) sB4[i] = gw[i];
    }
    __syncthreads();
    const short* sB = (const short*)sB4;

    int lane = tid & 63, wv = tid >> 6;
    int q = lane >> 4, lm = lane & 15;

    #pragma unroll 1
    for (int g = 0; g < 2; ++g) {
        int n0 = (blockIdx.x * 8 + wv + g * 4) * 16;
        if (n0 >= N) continue;
        int nr = n0 + lm;

        float4 at0 = *(const float4*)(attrs + (size_t)nr * 8);
        float4 at1 = *(const float4*)(attrs + (size_t)nr * 8 + 4);
        float at[8] = {at0.x, at0.y, at0.z, at0.w, at1.x, at1.y, at1.z, at1.w};

        const float* asp = agg_s + (size_t)nr * 64;
        bf16x8 aS[2];
        #pragma unroll
        for (int kc = 0; kc < 2; ++kc)
            aS[kc] = pack8(*(const float4*)(asp + kc * 32 + q * 8),
                           *(const float4*)(asp + kc * 32 + q * 8 + 4));

        const float* nsp = node_s + (size_t)nr * 32;
        bf16x8 scs[8];
        #pragma unroll
        for (int t = 0; t < 8; ++t) {
            float nv_ = nsp[t * 4 + q];
            #pragma unroll
            for (int j = 0; j < 8; ++j) scs[t][j] = f2b(nv_ * at[j]);
        }

        #pragma unroll
        for (int nt = 0; nt < 2; ++nt) {
            f32x4 acc = (f32x4){0.f, 0.f, 0.f, 0.f};
            acc = __builtin_amdgcn_mfma_f32_16x16x32_bf16(
                aS[0], *(const bf16x8*)&sB[(nt * 2 + 0) * 512 + lane * 8], acc, 0, 0, 0);
            acc = __builtin_amdgcn_mfma_f32_16x16x32_bf16(
                aS[1], *(const bf16x8*)&sB[(nt * 2 + 1) * 512 + lane * 8], acc, 0, 0, 0);
            #pragma unroll
            for (int t = 0; t < 8; ++t)
                acc = __builtin_amdgcn_mfma_f32_16x16x32_bf16(
                    scs[t], *(const bf16x8*)&sB[(8 + nt * 8 + t) * 512 + lane * 8], acc, 0, 0, 0);
            #pragma unroll
            for (int r = 0; r < 4; ++r)
                out[(size_t)(n0 + q * 4 + r) * 128 + nt * 16 + lm] = acc[r];
        }

        const float* nvp = node_v + (size_t)nr * 96;
        const float* avp = agg_v + (size_t)nr * 192;
        #pragma unroll
        for (int i = 0; i < 3; ++i) {
            bf16x8 aV[2];
            #pragma unroll
            for (int kc = 0; kc < 2; ++kc)
                aV[kc] = pack8(*(const float4*)(avp + i * 64 + kc * 32 + q * 8),
                               *(const float4*)(avp + i * 64 + kc * 32 + q * 8 + 4));
            bf16x8 scv[8];
            #pragma unroll
            for (int t = 0; t < 8; ++t) {
                float nv_ = nvp[(t * 4 + q) * 3 + i];
                #pragma unroll
                for (int j = 0; j < 8; ++j) scv[t][j] = f2b(nv_ * at[j]);
            }
            #pragma unroll
            for (int nt = 0; nt < 2; ++nt) {
                f32x4 acc = (f32x4){0.f, 0.f, 0.f, 0.f};
                acc = __builtin_amdgcn_mfma_f32_16x16x32_bf16(
                    aV[0], *(const bf16x8*)&sB[(4 + nt * 2 + 0) * 512 + lane * 8], acc, 0, 0, 0);
                acc = __builtin_amdgcn_mfma_f32_16x16x32_bf16(
                    aV[1], *(const bf16x8*)&sB[(4 + nt * 2 + 1) * 512 + lane * 8], acc, 0, 0, 0);
                #pragma unroll
                for (int t = 0; t < 8; ++t)
                    acc = __builtin_amdgcn_mfma_f32_16x16x32_bf16(
                        scv[t], *(const bf16x8*)&sB[(24 + nt * 8 + t) * 512 + lane * 8], acc, 0, 0, 0);
                #pragma unroll
                for (int r = 0; r < 4; ++r)
                    out[(size_t)(n0 + q * 4 + r) * 128 + 32 + (nt * 16 + lm) * 3 + i] = acc[r];
            }
        }
    }
}

extern "C" void kernel_launch(void* const* d_in, const int* in_sizes, int n_in,
                              void* d_out, int out_size, void* d_ws, size_t ws_size,
                              hipStream_t stream)
{
    const float* node_s = (const float*)d_in[0];
    const float* node_v = (const float*)d_in[1];
    const float* attrs  = (const float*)d_in[2];
    const float* emb    = (const float*)d_in[3];
    const float* y1     = (const float*)d_in[5];
    const int*   eidx   = (const int*)d_in[6];
    const float* W1s  = (const float*)d_in[7];
    const float* W1v  = (const float*)d_in[8];
    const float* Wr1  = (const float*)d_in[9];
    const float* Wr2  = (const float*)d_in[10];
    const float* W2s  = (const float*)d_in[11];
    const float* W2v  = (const float*)d_in[12];
    const float* Wscs = (const float*)d_in[13];
    const float* Wscv = (const float*)d_in[14];

    int N = in_sizes[0] / 32;   // 20000
    int E = in_sizes[3] / 16;   // 640000

    float* agg_s = (float*)d_ws;                       // N*64
    float* agg_v = agg_s + (size_t)N * 64;             // N*192
    short* feat  = (short*)(agg_v + (size_t)N * 192);  // N*128 bf16 (packed {s,vx,vy,vz})
    int* count   = (int*)(feat + (size_t)N * 128);     // 4N (sharded)
    int* cursor  = count + (size_t)4 * N;              // 4N
    int2* epair  = (int2*)(cursor + (size_t)4 * N);    // E (8B: e, dst)
    int* bsum    = (int*)(epair + E);                  // scan block sums (1024)
    short* wsB   = (short*)(bsum + 1024);              // k_out weights, 20480 bf16 (40KB)

    (void)hipMemsetAsync(count, 0, (size_t)4 * N * sizeof(int), stream);

    int M  = 4 * N;                          // sharded count length (80000)
    int NB = (M + 255) / 256;                // scan blocks (313)
    int nblin  = (N + 63) / 64;              // 64 nodes (4 wave-tiles) per block
    int nbhist = (E + 1023) / 1024;          // histogram: 4 edges/thread (625)
    int nagg4  = N * 64;                     // N*256 floats / 4
    int nbz    = (nagg4 + 1023) / 1024;
    int nbw    = (20480 + 1023) / 1024;      // k_out weight prep (20 blocks)
    k_lin1h<<<dim3(nblin + nbhist + nbz + nbw), dim3(256), 0, stream>>>(
        node_s, node_v, W1s, W1v, feat, N,
        eidx, count, E, (float4*)agg_s, nagg4, nblin, nbhist, nbz,
        W2s, W2v, Wscs, Wscv, wsB);
    k_scanA<<<dim3(NB), dim3(256), 0, stream>>>(count, bsum, M);
    k_scanC<<<dim3(NB), dim3(256), 0, stream>>>(count, bsum, cursor, M);
    k_fill<<<dim3((E + 255) / 256), dim3(256), 0, stream>>>(eidx, cursor, epair, E);
    k_fused<<<dim3((E + 255) / 256), dim3(256), 0, stream>>>(emb, epair, eidx, y1,
                                                             Wr1, Wr2, feat,
                                                             agg_s, agg_v, E);
    k_out<<<dim3((N + 127) / 128), dim3(256), 0, stream>>>(node_s, node_v, attrs, agg_s, agg_v,
                                                           wsB, (float*)d_out, N);
}